// Round 3
// baseline (955.849 us; speedup 1.0000x reference)
//
#include <hip/hip_runtime.h>
#include <math.h>

#define NUM_LEVELS 16
#define T_SIZE (1u << 19)
#define T_MASK (T_SIZE - 1u)
#define PRIME1 2654435761u
#define PRIME2 805459861u

struct ResParams { float r[NUM_LEVELS]; };

typedef float f32x2 __attribute__((ext_vector_type(2)));
typedef float f32x4 __attribute__((ext_vector_type(4)));

// Corner hash indices + fractional weights for one (point, level).
struct CornerSet {
    unsigned idx[8];
    unsigned ux;       // integer x cell coord (parity decides paired loads)
    float fx, fy, fz;
};

// Takes PRE-NORMALIZED coords (hoisted out of the level loop).
__device__ __forceinline__ void calc_corners_n(
    float nx, float ny, float nz, float res, unsigned base, CornerSet& cs)
{
    float sx = nx * res, sy = ny * res, sz = nz * res;
    float flx = floorf(sx), fly = floorf(sy), flz = floorf(sz);
    cs.fx = sx - flx; cs.fy = sy - fly; cs.fz = sz - flz;

    unsigned ux = (unsigned)(int)flx;
    unsigned uy = (unsigned)(int)fly;
    unsigned uz = (unsigned)(int)flz;
    cs.ux = ux;

    unsigned hx0 = ux;            unsigned hx1 = ux + 1u;
    unsigned hy0 = uy * PRIME1;   unsigned hy1 = hy0 + PRIME1;
    unsigned hz0 = uz * PRIME2;   unsigned hz1 = hz0 + PRIME2;

    cs.idx[0] = base + ((hx0 ^ hy0 ^ hz0) & T_MASK);
    cs.idx[1] = base + ((hx0 ^ hy0 ^ hz1) & T_MASK);
    cs.idx[2] = base + ((hx0 ^ hy1 ^ hz0) & T_MASK);
    cs.idx[3] = base + ((hx0 ^ hy1 ^ hz1) & T_MASK);
    cs.idx[4] = base + ((hx1 ^ hy0 ^ hz0) & T_MASK);
    cs.idx[5] = base + ((hx1 ^ hy0 ^ hz1) & T_MASK);
    cs.idx[6] = base + ((hx1 ^ hy1 ^ hz0) & T_MASK);
    cs.idx[7] = base + ((hx1 ^ hy1 ^ hz1) & T_MASK);
}

// PRIMES[0]==1 => for even ux the x1-corner hash is h0^1: the two x-corners of
// each (y,z) pair sit in ADJACENT table slots -> one aligned 16B load covers
// both (4 requests, 64B). Odd ux keeps 8 independent 8B gathers (8 req, 64B).
// Avg 6 requests / 64 bytes per point-level. (Round-1 form: measured best.
// Round-2's "unconditional pair + tail" raised bytes/pt-level 64->80 and
// regressed 385->439us — do not reintroduce.)
__device__ __forceinline__ void load_feats(
    const float2* __restrict__ table, const CornerSet& cs, float2 f[8])
{
    if ((cs.ux & 1u) == 0u) {
        const f32x4* t4 = reinterpret_cast<const f32x4*>(table);
#pragma unroll
        for (int j = 0; j < 4; ++j) {
            unsigned i0 = cs.idx[j];            // x0 corner; x1 corner = i0^1
            f32x4 v = t4[i0 >> 1];              // 16B-aligned pair {i0&~1, i0|1}
            float2 lo; lo.x = v.x; lo.y = v.y;  // slot (i0 & ~1)
            float2 hi; hi.x = v.z; hi.y = v.w;  // slot (i0 | 1)
            bool sw = (i0 & 1u) != 0u;
            f[j]     = sw ? hi : lo;            // corner x0 = slot i0
            f[4 + j] = sw ? lo : hi;            // corner x1 = slot i0^1
        }
    } else {
#pragma unroll
        for (int i = 0; i < 8; ++i) f[i] = table[cs.idx[i]];
    }
}

__device__ __forceinline__ float2 trilerp(const float2 f[8], float fx, float fy, float fz)
{
    float omz = 1.0f - fz, omy = 1.0f - fy, omx = 1.0f - fx;
    float c00x = f[0].x * omz + f[1].x * fz;
    float c00y = f[0].y * omz + f[1].y * fz;
    float c01x = f[2].x * omz + f[3].x * fz;
    float c01y = f[2].y * omz + f[3].y * fz;
    float c10x = f[4].x * omz + f[5].x * fz;
    float c10y = f[4].y * omz + f[5].y * fz;
    float c11x = f[6].x * omz + f[7].x * fz;
    float c11y = f[6].y * omz + f[7].y * fz;
    float c0x = c00x * omy + c01x * fy;
    float c0y = c00y * omy + c01y * fy;
    float c1x = c10x * omy + c11x * fy;
    float c1y = c10y * omy + c11y * fy;
    float2 o;
    o.x = c0x * omx + c1x * fx;
    o.y = c0y * omx + c1y * fx;
    return o;
}

// ---------------- Fused single pass ----------------
// One thread per point. Rolled loop over 8 level-PAIRS, identical order in
// every block => all resident waves sweep the 16 tables roughly in lockstep,
// preserving the one-4MB-table-at-a-time L2 residency that the old two-pass
// level-phased dispatch had — WITHOUT materializing the 256MB ws roundtrip
// or the 170us untile kernel.
// Per pair: compute 2 levels, store one 16B chunk of out[n][32] immediately
// (no runtime-indexed accumulator -> no scratch). Each point's 128B output
// line is filled by 8 temporally-close stores from the SAME thread; L2/L3
// merge them (out = 128MB < 256MB L3).
__global__ __launch_bounds__(256) void hashgrid_fused16_kernel(
    const float* __restrict__ pos,      // [N,3]
    const float2* __restrict__ table,   // [L*T]
    float* __restrict__ out,            // [N][32] floats
    ResParams rp, int N)
{
    int n = blockIdx.x * 256 + threadIdx.x;
    if (n >= N) return;

    float px = pos[3 * n + 0], py = pos[3 * n + 1], pz = pos[3 * n + 2];

    // normalized = (p+1)/(2+1e-8); float32(2+1e-8)==2.0f so *0.5f is bit-identical
    const float HI = 0.999999f;  // float32(1.0 - 1e-6)
    float nx = fminf(fmaxf((px + 1.0f) * 0.5f, 0.0f), HI);
    float ny = fminf(fmaxf((py + 1.0f) * 0.5f, 0.0f), HI);
    float nz = fminf(fmaxf((pz + 1.0f) * 0.5f, 0.0f), HI);

    float* po = out + (size_t)n * 32;

#pragma unroll 1
    for (int pr = 0; pr < 8; ++pr) {
        int l0 = 2 * pr;
        int l1 = 2 * pr + 1;

        CornerSet c0, c1;
        calc_corners_n(nx, ny, nz, rp.r[l0], (unsigned)l0 * T_SIZE, c0);
        calc_corners_n(nx, ny, nz, rp.r[l1], (unsigned)l1 * T_SIZE, c1);

        float2 f0[8], f1[8];
        load_feats(table, c0, f0);
        load_feats(table, c1, f1);

        float2 o0 = trilerp(f0, c0.fx, c0.fy, c0.fz);
        float2 o1 = trilerp(f1, c1.fx, c1.fy, c1.fz);

        f32x4 v; v.x = o0.x; v.y = o0.y; v.z = o1.x; v.w = o1.y;
        *reinterpret_cast<f32x4*>(po + 4 * pr) = v;   // 16B-aligned
    }
}

extern "C" void kernel_launch(void* const* d_in, const int* in_sizes, int n_in,
                              void* d_out, int out_size, void* d_ws, size_t ws_size,
                              hipStream_t stream) {
    const float*  pos   = (const float*)d_in[0];
    const float2* table = (const float2*)d_in[1];
    int N = in_sizes[0] / 3;

    ResParams rp;
    double growth = exp((log(2048.0) - log(16.0)) / 15.0);
    for (int l = 0; l < NUM_LEVELS; ++l) {
        rp.r[l] = (float)ceil(16.0 * pow(growth, (double)l));
    }

    int blocks = (N + 255) / 256;
    hashgrid_fused16_kernel<<<blocks, 256, 0, stream>>>(
        pos, table, (float*)d_out, rp, N);
}

// Round 4
// 880.116 us; speedup vs baseline: 1.0860x; 1.0860x over previous
//
#include <hip/hip_runtime.h>
#include <math.h>

#define NUM_LEVELS 16
#define T_SIZE (1u << 19)
#define T_MASK (T_SIZE - 1u)
#define PRIME1 2654435761u
#define PRIME2 805459861u

struct ResParams { float r[NUM_LEVELS]; };

typedef float f32x2 __attribute__((ext_vector_type(2)));
typedef float f32x4 __attribute__((ext_vector_type(4)));

__device__ __forceinline__ void nt_store_f4(f32x4 v, float* p) {
    __builtin_nontemporal_store(v, (f32x4*)p);
}

// Corner hash indices + fractional weights for one (point, level).
struct CornerSet {
    unsigned idx[8];
    unsigned ux;       // integer x cell coord (parity decides paired loads)
    float fx, fy, fz;
};

// Takes PRE-NORMALIZED coords (hoisted out of the level loop).
__device__ __forceinline__ void calc_corners_n(
    float nx, float ny, float nz, float res, unsigned base, CornerSet& cs)
{
    float sx = nx * res, sy = ny * res, sz = nz * res;
    float flx = floorf(sx), fly = floorf(sy), flz = floorf(sz);
    cs.fx = sx - flx; cs.fy = sy - fly; cs.fz = sz - flz;

    unsigned ux = (unsigned)(int)flx;
    unsigned uy = (unsigned)(int)fly;
    unsigned uz = (unsigned)(int)flz;
    cs.ux = ux;

    unsigned hx0 = ux;            unsigned hx1 = ux + 1u;
    unsigned hy0 = uy * PRIME1;   unsigned hy1 = hy0 + PRIME1;
    unsigned hz0 = uz * PRIME2;   unsigned hz1 = hz0 + PRIME2;

    cs.idx[0] = base + ((hx0 ^ hy0 ^ hz0) & T_MASK);
    cs.idx[1] = base + ((hx0 ^ hy0 ^ hz1) & T_MASK);
    cs.idx[2] = base + ((hx0 ^ hy1 ^ hz0) & T_MASK);
    cs.idx[3] = base + ((hx0 ^ hy1 ^ hz1) & T_MASK);
    cs.idx[4] = base + ((hx1 ^ hy0 ^ hz0) & T_MASK);
    cs.idx[5] = base + ((hx1 ^ hy0 ^ hz1) & T_MASK);
    cs.idx[6] = base + ((hx1 ^ hy1 ^ hz0) & T_MASK);
    cs.idx[7] = base + ((hx1 ^ hy1 ^ hz1) & T_MASK);
}

// PRIMES[0]==1 => for even ux the x1-corner hash is h0^1: the two x-corners of
// each (y,z) pair sit in ADJACENT table slots -> one aligned 16B load covers
// both (4 requests, 64B). Odd ux keeps 8 independent 8B gathers (8 req, 64B).
// Avg 6 requests / 64 bytes per point-level. Round-1 divergent form: measured
// best (round-2's unconditional-pair+tail raised bytes 64->80, regressed).
__device__ __forceinline__ void load_feats(
    const float2* __restrict__ table, const CornerSet& cs, float2 f[8])
{
    if ((cs.ux & 1u) == 0u) {
        const f32x4* t4 = reinterpret_cast<const f32x4*>(table);
#pragma unroll
        for (int j = 0; j < 4; ++j) {
            unsigned i0 = cs.idx[j];            // x0 corner; x1 corner = i0^1
            f32x4 v = t4[i0 >> 1];              // 16B-aligned pair {i0&~1, i0|1}
            float2 lo; lo.x = v.x; lo.y = v.y;  // slot (i0 & ~1)
            float2 hi; hi.x = v.z; hi.y = v.w;  // slot (i0 | 1)
            bool sw = (i0 & 1u) != 0u;
            f[j]     = sw ? hi : lo;            // corner x0 = slot i0
            f[4 + j] = sw ? lo : hi;            // corner x1 = slot i0^1
        }
    } else {
#pragma unroll
        for (int i = 0; i < 8; ++i) f[i] = table[cs.idx[i]];
    }
}

__device__ __forceinline__ float2 trilerp(const float2 f[8], float fx, float fy, float fz)
{
    float omz = 1.0f - fz, omy = 1.0f - fy, omx = 1.0f - fx;
    float c00x = f[0].x * omz + f[1].x * fz;
    float c00y = f[0].y * omz + f[1].y * fz;
    float c01x = f[2].x * omz + f[3].x * fz;
    float c01y = f[2].y * omz + f[3].y * fz;
    float c10x = f[4].x * omz + f[5].x * fz;
    float c10y = f[4].y * omz + f[5].y * fz;
    float c11x = f[6].x * omz + f[7].x * fz;
    float c11y = f[6].y * omz + f[7].y * fz;
    float c0x = c00x * omy + c01x * fy;
    float c0y = c00y * omy + c01y * fy;
    float c1x = c10x * omy + c11x * fy;
    float c1y = c10y * omy + c11y * fy;
    float2 o;
    o.x = c0x * omx + c1x * fx;
    o.y = c0y * omx + c1y * fx;
    return o;
}

// ---------------- Persistent fused kernel ----------------
// ALL blocks co-resident (<=2048 blocks of 256 thr at <=64 VGPR => 8 blk/CU),
// so there is no block turnover: every block sweeps levels 0..15 in the same
// order at the same statistical rate. At any instant ~one 4MB level table is
// hot per XCD L2 (the round-1 phasing win) while positions/normalized coords
// live in registers across all 16 levels and output chunks are stored
// directly in final [N][32] layout at every odd level (no ws, no 2nd pass).
// Round-3's failure mode (3906 blocks, second cohort restarting at level 0 ->
// many tables live -> FETCH 2.67GB) is structurally impossible here.
// Output nt-stores bypass L2 (protect table residency); partial 16B line
// fills merge in L3 (measured cost ~+123MB writes in round 3 — acceptable).
__global__ __launch_bounds__(256, 8) void hashgrid_persistent_kernel(
    const float* __restrict__ pos,      // [N,3]
    const float2* __restrict__ table,   // [L*T]
    float* __restrict__ out,            // [N][32] floats
    ResParams rp, int N)
{
    int n0 = (blockIdx.x * 256 + threadIdx.x) * 2;
    int n1 = n0 + 1;
    bool v0 = n0 < N;
    bool v1 = n1 < N;
    if (!v0) return;
    int m1 = v1 ? n1 : n0;  // safe address for inactive second point

    float px0 = pos[3 * n0 + 0], py0 = pos[3 * n0 + 1], pz0 = pos[3 * n0 + 2];
    float px1 = pos[3 * m1 + 0], py1 = pos[3 * m1 + 1], pz1 = pos[3 * m1 + 2];

    // normalized = (p+1)/(2+1e-8); float32(2+1e-8)==2.0f so *0.5f is bit-identical
    const float HI = 0.999999f;  // float32(1.0 - 1e-6)
    float nx0 = fminf(fmaxf((px0 + 1.0f) * 0.5f, 0.0f), HI);
    float ny0 = fminf(fmaxf((py0 + 1.0f) * 0.5f, 0.0f), HI);
    float nz0 = fminf(fmaxf((pz0 + 1.0f) * 0.5f, 0.0f), HI);
    float nx1 = fminf(fmaxf((px1 + 1.0f) * 0.5f, 0.0f), HI);
    float ny1 = fminf(fmaxf((py1 + 1.0f) * 0.5f, 0.0f), HI);
    float nz1 = fminf(fmaxf((pz1 + 1.0f) * 0.5f, 0.0f), HI);

    float* po0 = out + (size_t)n0 * 32;
    float* po1 = out + (size_t)n1 * 32;

    float ox0 = 0.f, oy0 = 0.f, ox1 = 0.f, oy1 = 0.f;  // prev (even) level out

#pragma unroll 1
    for (int l = 0; l < NUM_LEVELS; ++l) {
        float res = rp.r[l];                 // uniform s_load from kernarg
        unsigned base = (unsigned)l * T_SIZE;

        CornerSet c0, c1;
        calc_corners_n(nx0, ny0, nz0, res, base, c0);
        calc_corners_n(nx1, ny1, nz1, res, base, c1);

        float2 f0[8], f1[8];
        load_feats(table, c0, f0);
        load_feats(table, c1, f1);

        float2 o0 = trilerp(f0, c0.fx, c0.fy, c0.fz);
        float2 o1 = trilerp(f1, c1.fx, c1.fy, c1.fz);

        if (l & 1) {                          // wave-uniform branch
            int ch = (l >> 1) * 4;
            f32x4 w0; w0.x = ox0; w0.y = oy0; w0.z = o0.x; w0.w = o0.y;
            nt_store_f4(w0, po0 + ch);        // 16B-aligned chunk of out[n0]
            if (v1) {
                f32x4 w1; w1.x = ox1; w1.y = oy1; w1.z = o1.x; w1.w = o1.y;
                nt_store_f4(w1, po1 + ch);
            }
        } else {
            ox0 = o0.x; oy0 = o0.y;
            ox1 = o1.x; oy1 = o1.y;
        }
    }
}

// ---------------- Fallback (grid would exceed residency): fused per-point ----
__global__ __launch_bounds__(256) void hashgrid_fused16_kernel(
    const float* __restrict__ pos,
    const float2* __restrict__ table,
    float* __restrict__ out,
    ResParams rp, int N)
{
    int n = blockIdx.x * 256 + threadIdx.x;
    if (n >= N) return;
    float px = pos[3 * n + 0], py = pos[3 * n + 1], pz = pos[3 * n + 2];
    const float HI = 0.999999f;
    float nx = fminf(fmaxf((px + 1.0f) * 0.5f, 0.0f), HI);
    float ny = fminf(fmaxf((py + 1.0f) * 0.5f, 0.0f), HI);
    float nz = fminf(fmaxf((pz + 1.0f) * 0.5f, 0.0f), HI);
    float* po = out + (size_t)n * 32;
#pragma unroll 1
    for (int pr = 0; pr < 8; ++pr) {
        CornerSet c0, c1;
        calc_corners_n(nx, ny, nz, rp.r[2 * pr],     (unsigned)(2 * pr) * T_SIZE, c0);
        calc_corners_n(nx, ny, nz, rp.r[2 * pr + 1], (unsigned)(2 * pr + 1) * T_SIZE, c1);
        float2 f0[8], f1[8];
        load_feats(table, c0, f0);
        load_feats(table, c1, f1);
        float2 o0 = trilerp(f0, c0.fx, c0.fy, c0.fz);
        float2 o1 = trilerp(f1, c1.fx, c1.fy, c1.fz);
        f32x4 v; v.x = o0.x; v.y = o0.y; v.z = o1.x; v.w = o1.y;
        *reinterpret_cast<f32x4*>(po + 4 * pr) = v;
    }
}

extern "C" void kernel_launch(void* const* d_in, const int* in_sizes, int n_in,
                              void* d_out, int out_size, void* d_ws, size_t ws_size,
                              hipStream_t stream) {
    const float*  pos   = (const float*)d_in[0];
    const float2* table = (const float2*)d_in[1];
    int N = in_sizes[0] / 3;

    ResParams rp;
    double growth = exp((log(2048.0) - log(16.0)) / 15.0);
    for (int l = 0; l < NUM_LEVELS; ++l) {
        rp.r[l] = (float)ceil(16.0 * pow(growth, (double)l));
    }

    int blocks = (N + 511) / 512;   // 2 points per thread
    if (blocks <= 2048) {
        // all blocks co-resident (8 blocks/CU @ <=64 VGPR) -> level lockstep
        hashgrid_persistent_kernel<<<blocks, 256, 0, stream>>>(
            pos, table, (float*)d_out, rp, N);
    } else {
        int fb = (N + 255) / 256;
        hashgrid_fused16_kernel<<<fb, 256, 0, stream>>>(
            pos, table, (float*)d_out, rp, N);
    }
}

// Round 5
// 799.085 us; speedup vs baseline: 1.1962x; 1.1014x over previous
//
#include <hip/hip_runtime.h>
#include <math.h>

#define NUM_LEVELS 16
#define T_SIZE (1u << 19)
#define T_MASK (T_SIZE - 1u)
#define PRIME1 2654435761u
#define PRIME2 805459861u

struct ResParams { float r[NUM_LEVELS]; };

typedef float f32x2 __attribute__((ext_vector_type(2)));
typedef float f32x4 __attribute__((ext_vector_type(4)));

__device__ __forceinline__ void nt_store_f2(float2 v, float* p) {
    f32x2 x; x.x = v.x; x.y = v.y;
    __builtin_nontemporal_store(x, (f32x2*)p);
}

// Corner hash indices + fractional weights for one (point, level).
struct CornerSet {
    unsigned idx[8];
    unsigned ux;       // integer x cell coord (parity decides paired loads)
    float fx, fy, fz;
};

__device__ __forceinline__ void calc_corners(
    float px, float py, float pz, float res, unsigned base, CornerSet& cs)
{
    // normalized = (p+1)/(2+1e-8); float32(2+1e-8)==2.0f so *0.5f is bit-identical
    float nx = (px + 1.0f) * 0.5f;
    float ny = (py + 1.0f) * 0.5f;
    float nz = (pz + 1.0f) * 0.5f;
    const float HI = 0.999999f;  // float32(1.0 - 1e-6)
    nx = fminf(fmaxf(nx, 0.0f), HI);
    ny = fminf(fmaxf(ny, 0.0f), HI);
    nz = fminf(fmaxf(nz, 0.0f), HI);

    float sx = nx * res, sy = ny * res, sz = nz * res;
    float flx = floorf(sx), fly = floorf(sy), flz = floorf(sz);
    cs.fx = sx - flx; cs.fy = sy - fly; cs.fz = sz - flz;

    unsigned ux = (unsigned)(int)flx;
    unsigned uy = (unsigned)(int)fly;
    unsigned uz = (unsigned)(int)flz;
    cs.ux = ux;

    unsigned hx0 = ux;            unsigned hx1 = ux + 1u;
    unsigned hy0 = uy * PRIME1;   unsigned hy1 = hy0 + PRIME1;
    unsigned hz0 = uz * PRIME2;   unsigned hz1 = hz0 + PRIME2;

    cs.idx[0] = base + ((hx0 ^ hy0 ^ hz0) & T_MASK);
    cs.idx[1] = base + ((hx0 ^ hy0 ^ hz1) & T_MASK);
    cs.idx[2] = base + ((hx0 ^ hy1 ^ hz0) & T_MASK);
    cs.idx[3] = base + ((hx0 ^ hy1 ^ hz1) & T_MASK);
    cs.idx[4] = base + ((hx1 ^ hy0 ^ hz0) & T_MASK);
    cs.idx[5] = base + ((hx1 ^ hy0 ^ hz1) & T_MASK);
    cs.idx[6] = base + ((hx1 ^ hy1 ^ hz0) & T_MASK);
    cs.idx[7] = base + ((hx1 ^ hy1 ^ hz1) & T_MASK);
}

// PRIMES[0]==1 => for even ux the x1-corner hash is h0^1: the two x-corners of
// each (y,z) pair sit in ADJACENT table slots -> one aligned 16B load covers
// both (4 requests, 64B). Odd ux keeps 8 independent 8B gathers (8 req, 64B).
// Avg 6 requests / 64 bytes per point-level. Round-1 divergent form: measured
// best (round-2's unconditional-pair+tail raised bytes 64->80, regressed).
__device__ __forceinline__ void load_feats(
    const float2* __restrict__ table, const CornerSet& cs, float2 f[8])
{
    if ((cs.ux & 1u) == 0u) {
        const f32x4* t4 = reinterpret_cast<const f32x4*>(table);
#pragma unroll
        for (int j = 0; j < 4; ++j) {
            unsigned i0 = cs.idx[j];            // x0 corner; x1 corner = i0^1
            f32x4 v = t4[i0 >> 1];              // 16B-aligned pair {i0&~1, i0|1}
            float2 lo; lo.x = v.x; lo.y = v.y;  // slot (i0 & ~1)
            float2 hi; hi.x = v.z; hi.y = v.w;  // slot (i0 | 1)
            bool sw = (i0 & 1u) != 0u;
            f[j]     = sw ? hi : lo;            // corner x0 = slot i0
            f[4 + j] = sw ? lo : hi;            // corner x1 = slot i0^1
        }
    } else {
#pragma unroll
        for (int i = 0; i < 8; ++i) f[i] = table[cs.idx[i]];
    }
}

__device__ __forceinline__ float2 trilerp(const float2 f[8], float fx, float fy, float fz)
{
    float omz = 1.0f - fz, omy = 1.0f - fy, omx = 1.0f - fx;
    float c00x = f[0].x * omz + f[1].x * fz;
    float c00y = f[0].y * omz + f[1].y * fz;
    float c01x = f[2].x * omz + f[3].x * fz;
    float c01y = f[2].y * omz + f[3].y * fz;
    float c10x = f[4].x * omz + f[5].x * fz;
    float c10y = f[4].y * omz + f[5].y * fz;
    float c11x = f[6].x * omz + f[7].x * fz;
    float c11y = f[6].y * omz + f[7].y * fz;
    float c0x = c00x * omy + c01x * fy;
    float c0y = c00y * omy + c01y * fy;
    float c1x = c10x * omy + c11x * fy;
    float c1y = c10y * omy + c11y * fy;
    float2 o;
    o.x = c0x * omx + c1x * fx;
    o.y = c0y * omx + c1y * fx;
    return o;
}

// ---------------- Single pass: level-phased gather with DIRECT output ----------
// Structure identical to the round-1 champion gather (the only variant that
// held FETCH at ~570MB): level = blockIdx.y, dispatch x-fastest, so the
// in-flight block window spans <=2 levels and exactly one 4MB table is hot
// per XCD L2 per phase. Rounds 3/4 proved any non-dispatch-enforced phasing
// (loop-in-thread, persistent co-residency) drifts and thrashes L2 (FETCH
// 2.2-2.7GB, +370us).
// Difference vs round 1: each phase nt-stores its level's float2 DIRECTLY to
// the final out[n][32] slot (8B, bypassing L2; 16 partial writes per 128B
// line merge in L3: out=128MB < 256MB L3). This deletes the 256MB ws
// round-trip and the entire second kernel (~170us measured wall).
__global__ __launch_bounds__(256) void hashgrid_gather_direct_kernel(
    const float* __restrict__ pos,      // [N,3]
    const float2* __restrict__ table,   // [L*T]
    float* __restrict__ out,            // [N][32] floats
    ResParams rp, int N)
{
    int level = blockIdx.y;
    int t = threadIdx.x;
    int n0 = blockIdx.x * 512 + 2 * t;
    int n1 = n0 + 1;
    bool v0 = n0 < N;
    bool v1 = n1 < N;
    if (!v0) return;

    float res = rp.r[level];
    unsigned base = (unsigned)level * T_SIZE;

    float px0 = pos[3 * n0 + 0], py0 = pos[3 * n0 + 1], pz0 = pos[3 * n0 + 2];
    int m1 = v1 ? n1 : n0;  // safe address for inactive second point
    float px1 = pos[3 * m1 + 0], py1 = pos[3 * m1 + 1], pz1 = pos[3 * m1 + 2];

    CornerSet c0, c1;
    calc_corners(px0, py0, pz0, res, base, c0);
    calc_corners(px1, py1, pz1, res, base, c1);

    float2 f0[8], f1[8];
    load_feats(table, c0, f0);
    load_feats(table, c1, f1);

    float2 o0 = trilerp(f0, c0.fx, c0.fy, c0.fz);
    float2 o1 = trilerp(f1, c1.fx, c1.fy, c1.fz);

    // Direct store to final layout: out[n][2*level .. 2*level+1], 8B aligned.
    nt_store_f2(o0, out + (size_t)n0 * 32 + 2 * level);
    if (v1) nt_store_f2(o1, out + (size_t)n1 * 32 + 2 * level);
}

extern "C" void kernel_launch(void* const* d_in, const int* in_sizes, int n_in,
                              void* d_out, int out_size, void* d_ws, size_t ws_size,
                              hipStream_t stream) {
    const float*  pos   = (const float*)d_in[0];
    const float2* table = (const float2*)d_in[1];
    int N = in_sizes[0] / 3;

    ResParams rp;
    double growth = exp((log(2048.0) - log(16.0)) / 15.0);
    for (int l = 0; l < NUM_LEVELS; ++l) {
        rp.r[l] = (float)ceil(16.0 * pow(growth, (double)l));
    }

    int chunks = (N + 511) / 512;           // 2 points per thread
    dim3 grid(chunks, NUM_LEVELS);          // x-fastest => level-phased
    hashgrid_gather_direct_kernel<<<grid, 256, 0, stream>>>(
        pos, table, (float*)d_out, rp, N);
}

// Round 6
// 559.877 us; speedup vs baseline: 1.7072x; 1.4273x over previous
//
#include <hip/hip_runtime.h>
#include <math.h>

#define NUM_LEVELS 16
#define T_SIZE (1u << 19)
#define T_MASK (T_SIZE - 1u)
#define PRIME1 2654435761u
#define PRIME2 805459861u

#define LOW_LEVELS 2     // levels 0,1 served from LDS dense grids
#define LOW_PTS 8192     // points per low-level block
#define LOW_DIM 24       // max (res+1) over low levels: res[1]=23

struct ResParams { float r[NUM_LEVELS]; };

typedef float f32x2 __attribute__((ext_vector_type(2)));
typedef float f32x4 __attribute__((ext_vector_type(4)));

__device__ __forceinline__ void nt_store_f2(float2 v, float2* p) {
    f32x2 x; x.x = v.x; x.y = v.y;
    __builtin_nontemporal_store(x, (f32x2*)p);
}
__device__ __forceinline__ float2 nt_load_f2(const float2* p) {
    f32x2 x = __builtin_nontemporal_load((const f32x2*)p);
    float2 r; r.x = x.x; r.y = x.y; return r;
}
__device__ __forceinline__ void nt_store_f4(f32x4 v, float* p) {
    __builtin_nontemporal_store(v, (f32x4*)p);
}
__device__ __forceinline__ f32x4 nt_load_f4(const float* p) {
    return __builtin_nontemporal_load((const f32x4*)p);
}

// Corner hash indices + fractional weights for one (point, level).
struct CornerSet {
    unsigned idx[8];
    unsigned ux;       // integer x cell coord (parity decides paired loads)
    float fx, fy, fz;
};

__device__ __forceinline__ void calc_corners(
    float px, float py, float pz, float res, unsigned base, CornerSet& cs)
{
    // normalized = (p+1)/(2+1e-8); float32(2+1e-8)==2.0f so *0.5f is bit-identical
    float nx = (px + 1.0f) * 0.5f;
    float ny = (py + 1.0f) * 0.5f;
    float nz = (pz + 1.0f) * 0.5f;
    const float HI = 0.999999f;  // float32(1.0 - 1e-6)
    nx = fminf(fmaxf(nx, 0.0f), HI);
    ny = fminf(fmaxf(ny, 0.0f), HI);
    nz = fminf(fmaxf(nz, 0.0f), HI);

    float sx = nx * res, sy = ny * res, sz = nz * res;
    float flx = floorf(sx), fly = floorf(sy), flz = floorf(sz);
    cs.fx = sx - flx; cs.fy = sy - fly; cs.fz = sz - flz;

    unsigned ux = (unsigned)(int)flx;
    unsigned uy = (unsigned)(int)fly;
    unsigned uz = (unsigned)(int)flz;
    cs.ux = ux;

    unsigned hx0 = ux;            unsigned hx1 = ux + 1u;
    unsigned hy0 = uy * PRIME1;   unsigned hy1 = hy0 + PRIME1;
    unsigned hz0 = uz * PRIME2;   unsigned hz1 = hz0 + PRIME2;

    cs.idx[0] = base + ((hx0 ^ hy0 ^ hz0) & T_MASK);
    cs.idx[1] = base + ((hx0 ^ hy0 ^ hz1) & T_MASK);
    cs.idx[2] = base + ((hx0 ^ hy1 ^ hz0) & T_MASK);
    cs.idx[3] = base + ((hx0 ^ hy1 ^ hz1) & T_MASK);
    cs.idx[4] = base + ((hx1 ^ hy0 ^ hz0) & T_MASK);
    cs.idx[5] = base + ((hx1 ^ hy0 ^ hz1) & T_MASK);
    cs.idx[6] = base + ((hx1 ^ hy1 ^ hz0) & T_MASK);
    cs.idx[7] = base + ((hx1 ^ hy1 ^ hz1) & T_MASK);
}

// PRIMES[0]==1 => for even ux the x1-corner hash is h0^1: the two x-corners of
// each (y,z) pair sit in ADJACENT table slots -> one aligned 16B load covers
// both (4 requests, 64B). Odd ux keeps 8 independent 8B gathers (8 req, 64B).
// Avg 6 requests / 64 bytes per point-level: the request AND byte floor.
// (r2's unconditional-pair+tail kept 6 req but 80B -> regressed; keep this.)
__device__ __forceinline__ void load_feats(
    const float2* __restrict__ table, const CornerSet& cs, float2 f[8])
{
    if ((cs.ux & 1u) == 0u) {
        const f32x4* t4 = reinterpret_cast<const f32x4*>(table);
#pragma unroll
        for (int j = 0; j < 4; ++j) {
            unsigned i0 = cs.idx[j];            // x0 corner; x1 corner = i0^1
            f32x4 v = t4[i0 >> 1];              // 16B-aligned pair {i0&~1, i0|1}
            float2 lo; lo.x = v.x; lo.y = v.y;  // slot (i0 & ~1)
            float2 hi; hi.x = v.z; hi.y = v.w;  // slot (i0 | 1)
            bool sw = (i0 & 1u) != 0u;
            f[j]     = sw ? hi : lo;            // corner x0 = slot i0
            f[4 + j] = sw ? lo : hi;            // corner x1 = slot i0^1
        }
    } else {
#pragma unroll
        for (int i = 0; i < 8; ++i) f[i] = table[cs.idx[i]];
    }
}

__device__ __forceinline__ float2 trilerp(const float2 f[8], float fx, float fy, float fz)
{
    float omz = 1.0f - fz, omy = 1.0f - fy, omx = 1.0f - fx;
    float c00x = f[0].x * omz + f[1].x * fz;
    float c00y = f[0].y * omz + f[1].y * fz;
    float c01x = f[2].x * omz + f[3].x * fz;
    float c01y = f[2].y * omz + f[3].y * fz;
    float c10x = f[4].x * omz + f[5].x * fz;
    float c10y = f[4].y * omz + f[5].y * fz;
    float c11x = f[6].x * omz + f[7].x * fz;
    float c11y = f[6].y * omz + f[7].y * fz;
    float c0x = c00x * omy + c01x * fy;
    float c0y = c00y * omy + c01y * fy;
    float c1x = c10x * omy + c11x * fy;
    float c1y = c10y * omy + c11y * fy;
    float2 o;
    o.x = c0x * omx + c1x * fx;
    o.y = c0y * omx + c1y * fx;
    return o;
}

// ---------------- Pass 1a: levels 0-1 from LDS dense grids ----------------
// Levels 0,1 have (res+1)^3 = 17^3 / 24^3 reachable cells -> the WHOLE level
// fits in LDS (39KB / 110KB) as a dense [x][y][z] grid of hashed values.
// Each block stages the grid once (4913 / 13824 gathers from the L2-resident
// table) and serves 8192 points purely from the LDS pipe -> removes ~12M of
// the 96M L2 line-requests for ~4.6M staging requests. Hash is pure integer
// math -> staged values are bit-identical to direct gathers.
template<int R1>
__device__ __forceinline__ void lowlevel_body(
    const float* __restrict__ pos, const float2* __restrict__ table,
    float2* __restrict__ ws, float res, int level, int N, float2* cell)
{
    const int R1sq = R1 * R1;
    unsigned base = (unsigned)level * T_SIZE;

    for (int s = threadIdx.x; s < R1 * R1sq; s += 256) {
        int x = s / R1sq;            // compile-time divisor -> magic-mul
        int r = s - x * R1sq;
        int y = r / R1;
        int z = r - y * R1;
        unsigned h = ((unsigned)x ^ ((unsigned)y * PRIME1)
                                  ^ ((unsigned)z * PRIME2)) & T_MASK;
        cell[s] = table[base + h];
    }
    __syncthreads();

    int start = blockIdx.x * LOW_PTS;
    int end = start + LOW_PTS; if (end > N) end = N;
    const float HI = 0.999999f;  // float32(1.0 - 1e-6)
    for (int n = start + (int)threadIdx.x; n < end; n += 256) {
        float px = pos[3 * n + 0], py = pos[3 * n + 1], pz = pos[3 * n + 2];
        float nx = fminf(fmaxf((px + 1.0f) * 0.5f, 0.0f), HI);
        float ny = fminf(fmaxf((py + 1.0f) * 0.5f, 0.0f), HI);
        float nz = fminf(fmaxf((pz + 1.0f) * 0.5f, 0.0f), HI);
        float sx = nx * res, sy = ny * res, sz = nz * res;
        float flx = floorf(sx), fly = floorf(sy), flz = floorf(sz);
        float fx = sx - flx, fy = sy - fly, fz = sz - flz;
        int ix = (int)flx, iy = (int)fly, iz = (int)flz;
        int i000 = (ix * R1 + iy) * R1 + iz;

        // f[i*4+j*2+k] = cell(x+i, y+j, z+k): matches reference OFFSETS order.
        float2 f[8];
        f[0] = cell[i000];
        f[1] = cell[i000 + 1];
        f[2] = cell[i000 + R1];
        f[3] = cell[i000 + R1 + 1];
        f[4] = cell[i000 + R1sq];
        f[5] = cell[i000 + R1sq + 1];
        f[6] = cell[i000 + R1sq + R1];
        f[7] = cell[i000 + R1sq + R1 + 1];

        float2 o = trilerp(f, fx, fy, fz);
        nt_store_f2(o, &ws[(size_t)level * N + n]);  // consecutive n -> full lines
    }
}

__global__ __launch_bounds__(256, 1) void hashgrid_lowlevel_kernel(
    const float* __restrict__ pos,
    const float2* __restrict__ table,
    float2* __restrict__ ws,
    ResParams rp, int N)
{
    __shared__ float2 cell[LOW_DIM * LOW_DIM * LOW_DIM];  // 110,592 B
    int level = blockIdx.y;           // 0 or 1
    if (level == 0) lowlevel_body<17>(pos, table, ws, rp.r[0], 0, N, cell);
    else            lowlevel_body<24>(pos, table, ws, rp.r[1], 1, N, cell);
}

// ---------------- Pass 1b: level-phased gather, levels 2..15 ----------------
// Round-1 champion structure verbatim (the only variant holding FETCH at
// ~570MB): level = blockIdx.y (+2), dispatch x-fastest -> in-flight window
// spans <=2 levels -> one 4MB table hot per XCD L2. Rounds 3/4 proved any
// non-dispatch-enforced phasing drifts and thrashes (FETCH 2.2-2.7GB).
// Round 5 proved direct scattered 8B output stores RMW-amplify (WRITE 500MB,
// +315us) -> ws staging + coalesced untile is structurally required.
__global__ __launch_bounds__(256) void hashgrid_gather_kernel(
    const float* __restrict__ pos,      // [N,3]
    const float2* __restrict__ table,   // [L*T]
    float2* __restrict__ ws,            // [L][N]
    ResParams rp, int N)
{
    int level = blockIdx.y + LOW_LEVELS;
    int t = threadIdx.x;
    int n0 = blockIdx.x * 512 + 2 * t;
    int n1 = n0 + 1;
    bool v0 = n0 < N;
    bool v1 = n1 < N;
    if (!v0) return;

    float res = rp.r[level];
    unsigned base = (unsigned)level * T_SIZE;

    float px0 = pos[3 * n0 + 0], py0 = pos[3 * n0 + 1], pz0 = pos[3 * n0 + 2];
    int m1 = v1 ? n1 : n0;  // safe address for inactive second point
    float px1 = pos[3 * m1 + 0], py1 = pos[3 * m1 + 1], pz1 = pos[3 * m1 + 2];

    CornerSet c0, c1;
    calc_corners(px0, py0, pz0, res, base, c0);
    calc_corners(px1, py1, pz1, res, base, c1);

    float2 f0[8], f1[8];
    load_feats(table, c0, f0);
    load_feats(table, c1, f1);

    float2 o0 = trilerp(f0, c0.fx, c0.fy, c0.fz);
    float2 o1 = trilerp(f1, c1.fx, c1.fy, c1.fz);

    size_t w = (size_t)level * N + n0;   // n0 even -> 16B aligned
    if (v1) {
        f32x4 v; v.x = o0.x; v.y = o0.y; v.z = o1.x; v.w = o1.y;
        nt_store_f4(v, (float*)&ws[w]);
    } else {
        nt_store_f2(o0, &ws[w]);
    }
}

// ---------------- Pass 2: pair untile ws[L][N] -> out[N][32] ----------------
// Round-2 form (measured ~11us faster than single-point): full 128B-line
// coalescing both ways. No LDS, no syncthreads.
__global__ __launch_bounds__(256) void hashgrid_untile_kernel(
    const float2* __restrict__ ws,      // [L][N]
    float* __restrict__ out,            // [N][32] floats
    int N)
{
    int g = blockIdx.x * 256 + threadIdx.x;
    int q = g >> 3;                     // point-pair: points 2q, 2q+1
    int m = g & 7;                      // level pair (levels 2m, 2m+1)
    int p0 = 2 * q;
    if (p0 >= N) return;

    const float* wsf = (const float*)ws;
    if (p0 + 1 < N) {
        f32x4 a = nt_load_f4(&wsf[((size_t)(2 * m) * N + p0) * 2]);      // lvl 2m,   pts p0,p0+1
        f32x4 b = nt_load_f4(&wsf[((size_t)(2 * m + 1) * N + p0) * 2]);  // lvl 2m+1, pts p0,p0+1
        f32x4 v0; v0.x = a.x; v0.y = a.y; v0.z = b.x; v0.w = b.y;
        f32x4 v1; v1.x = a.z; v1.y = a.w; v1.z = b.z; v1.w = b.w;
        nt_store_f4(v0, &out[(size_t)p0 * 32 + m * 4]);
        nt_store_f4(v1, &out[(size_t)(p0 + 1) * 32 + m * 4]);
    } else {
        float2 a = nt_load_f2(&ws[(size_t)(2 * m) * N + p0]);
        float2 b = nt_load_f2(&ws[(size_t)(2 * m + 1) * N + p0]);
        f32x4 v; v.x = a.x; v.y = a.y; v.z = b.x; v.w = b.y;
        nt_store_f4(v, &out[(size_t)p0 * 32 + m * 4]);
    }
}

// ---------------- Fallback (ws too small): fused single-pass ----------------
__global__ __launch_bounds__(256) void hashgrid_fused16_kernel(
    const float* __restrict__ pos,
    const float2* __restrict__ table,
    float* __restrict__ out,
    ResParams rp, int N)
{
    int n = blockIdx.x * 256 + threadIdx.x;
    if (n >= N) return;
    float px = pos[3 * n + 0], py = pos[3 * n + 1], pz = pos[3 * n + 2];
    const float HI = 0.999999f;
    float nx = fminf(fmaxf((px + 1.0f) * 0.5f, 0.0f), HI);
    float ny = fminf(fmaxf((py + 1.0f) * 0.5f, 0.0f), HI);
    float nz = fminf(fmaxf((pz + 1.0f) * 0.5f, 0.0f), HI);
    float* po = out + (size_t)n * 32;
#pragma unroll 1
    for (int pr = 0; pr < 8; ++pr) {
        CornerSet c0, c1;
        calc_corners(px, py, pz, rp.r[2 * pr],     (unsigned)(2 * pr) * T_SIZE, c0);
        calc_corners(px, py, pz, rp.r[2 * pr + 1], (unsigned)(2 * pr + 1) * T_SIZE, c1);
        float2 f0[8], f1[8];
        load_feats(table, c0, f0);
        load_feats(table, c1, f1);
        float2 o0 = trilerp(f0, c0.fx, c0.fy, c0.fz);
        float2 o1 = trilerp(f1, c1.fx, c1.fy, c1.fz);
        f32x4 v; v.x = o0.x; v.y = o0.y; v.z = o1.x; v.w = o1.y;
        *reinterpret_cast<f32x4*>(po + 4 * pr) = v;
    }
}

extern "C" void kernel_launch(void* const* d_in, const int* in_sizes, int n_in,
                              void* d_out, int out_size, void* d_ws, size_t ws_size,
                              hipStream_t stream) {
    const float*  pos   = (const float*)d_in[0];
    const float2* table = (const float2*)d_in[1];
    int N = in_sizes[0] / 3;

    ResParams rp;
    double growth = exp((log(2048.0) - log(16.0)) / 15.0);
    for (int l = 0; l < NUM_LEVELS; ++l) {
        rp.r[l] = (float)ceil(16.0 * pow(growth, (double)l));
    }

    size_t ws_needed = (size_t)NUM_LEVELS * (size_t)N * sizeof(float2);
    if (ws_size >= ws_needed) {
        float2* ws = (float2*)d_ws;

        int lowblocks = (N + LOW_PTS - 1) / LOW_PTS;
        dim3 lgrid(lowblocks, LOW_LEVELS);
        hashgrid_lowlevel_kernel<<<lgrid, 256, 0, stream>>>(pos, table, ws, rp, N);

        int chunks = (N + 511) / 512;           // 2 points per thread
        dim3 ggrid(chunks, NUM_LEVELS - LOW_LEVELS);  // x-fastest => level-phased
        hashgrid_gather_kernel<<<ggrid, 256, 0, stream>>>(pos, table, ws, rp, N);

        long long tthreads = ((long long)(N + 1) / 2) * 8;
        int tblocks = (int)((tthreads + 255) / 256);
        hashgrid_untile_kernel<<<tblocks, 256, 0, stream>>>(ws, (float*)d_out, N);
    } else {
        int fb = (N + 255) / 256;
        hashgrid_fused16_kernel<<<fb, 256, 0, stream>>>(
            pos, table, (float*)d_out, rp, N);
    }
}

// Round 7
// 552.460 us; speedup vs baseline: 1.7302x; 1.0134x over previous
//
#include <hip/hip_runtime.h>
#include <math.h>

#define NUM_LEVELS 16
#define T_SIZE (1u << 19)
#define T_MASK (T_SIZE - 1u)
#define PRIME1 2654435761u
#define PRIME2 805459861u

#define LOW_LEVELS 2     // levels 0,1 served from LDS dense grids
#define LOW_PTS 8192     // points per low-level block
#define LOW_DIM 24       // max (res+1) over low levels: res[1]=23

struct ResParams { float r[NUM_LEVELS]; };

typedef float f32x2 __attribute__((ext_vector_type(2)));
typedef float f32x4 __attribute__((ext_vector_type(4)));

__device__ __forceinline__ void nt_store_f2(float2 v, float2* p) {
    f32x2 x; x.x = v.x; x.y = v.y;
    __builtin_nontemporal_store(x, (f32x2*)p);
}
__device__ __forceinline__ float2 nt_load_f2(const float2* p) {
    f32x2 x = __builtin_nontemporal_load((const f32x2*)p);
    float2 r; r.x = x.x; r.y = x.y; return r;
}
__device__ __forceinline__ void nt_store_f4(f32x4 v, float* p) {
    __builtin_nontemporal_store(v, (f32x4*)p);
}
__device__ __forceinline__ f32x4 nt_load_f4(const float* p) {
    return __builtin_nontemporal_load((const f32x4*)p);
}

// Corner hash indices + fractional weights for one (point, level).
struct CornerSet {
    unsigned idx[8];
    unsigned ux;       // integer x cell coord (parity decides paired loads)
    float fx, fy, fz;
};

__device__ __forceinline__ void calc_corners(
    float px, float py, float pz, float res, unsigned base, CornerSet& cs)
{
    // normalized = (p+1)/(2+1e-8); float32(2+1e-8)==2.0f so *0.5f is bit-identical
    float nx = (px + 1.0f) * 0.5f;
    float ny = (py + 1.0f) * 0.5f;
    float nz = (pz + 1.0f) * 0.5f;
    const float HI = 0.999999f;  // float32(1.0 - 1e-6)
    nx = fminf(fmaxf(nx, 0.0f), HI);
    ny = fminf(fmaxf(ny, 0.0f), HI);
    nz = fminf(fmaxf(nz, 0.0f), HI);

    float sx = nx * res, sy = ny * res, sz = nz * res;
    float flx = floorf(sx), fly = floorf(sy), flz = floorf(sz);
    cs.fx = sx - flx; cs.fy = sy - fly; cs.fz = sz - flz;

    unsigned ux = (unsigned)(int)flx;
    unsigned uy = (unsigned)(int)fly;
    unsigned uz = (unsigned)(int)flz;
    cs.ux = ux;

    unsigned hx0 = ux;            unsigned hx1 = ux + 1u;
    unsigned hy0 = uy * PRIME1;   unsigned hy1 = hy0 + PRIME1;
    unsigned hz0 = uz * PRIME2;   unsigned hz1 = hz0 + PRIME2;

    cs.idx[0] = base + ((hx0 ^ hy0 ^ hz0) & T_MASK);
    cs.idx[1] = base + ((hx0 ^ hy0 ^ hz1) & T_MASK);
    cs.idx[2] = base + ((hx0 ^ hy1 ^ hz0) & T_MASK);
    cs.idx[3] = base + ((hx0 ^ hy1 ^ hz1) & T_MASK);
    cs.idx[4] = base + ((hx1 ^ hy0 ^ hz0) & T_MASK);
    cs.idx[5] = base + ((hx1 ^ hy0 ^ hz1) & T_MASK);
    cs.idx[6] = base + ((hx1 ^ hy1 ^ hz0) & T_MASK);
    cs.idx[7] = base + ((hx1 ^ hy1 ^ hz1) & T_MASK);
}

// PRIMES[0]==1 => for even ux the x1-corner hash is h0^1: the two x-corners of
// each (y,z) pair sit in ADJACENT table slots -> one aligned 16B load covers
// both (4 requests, 64B). Odd ux keeps 8 independent 8B gathers (8 req, 64B).
// Measured request-cost model (r0/r1/r2/r6 fits): c8=3.73ps, c16=4.77ps
// chip-wide => this form is the floor (even: 4*c16, odd: 8*c8).
__device__ __forceinline__ void load_feats(
    const float2* __restrict__ table, const CornerSet& cs, float2 f[8])
{
    if ((cs.ux & 1u) == 0u) {
        const f32x4* t4 = reinterpret_cast<const f32x4*>(table);
#pragma unroll
        for (int j = 0; j < 4; ++j) {
            unsigned i0 = cs.idx[j];            // x0 corner; x1 corner = i0^1
            f32x4 v = t4[i0 >> 1];              // 16B-aligned pair {i0&~1, i0|1}
            float2 lo; lo.x = v.x; lo.y = v.y;  // slot (i0 & ~1)
            float2 hi; hi.x = v.z; hi.y = v.w;  // slot (i0 | 1)
            bool sw = (i0 & 1u) != 0u;
            f[j]     = sw ? hi : lo;            // corner x0 = slot i0
            f[4 + j] = sw ? lo : hi;            // corner x1 = slot i0^1
        }
    } else {
#pragma unroll
        for (int i = 0; i < 8; ++i) f[i] = table[cs.idx[i]];
    }
}

__device__ __forceinline__ float2 trilerp(const float2 f[8], float fx, float fy, float fz)
{
    float omz = 1.0f - fz, omy = 1.0f - fy, omx = 1.0f - fx;
    float c00x = f[0].x * omz + f[1].x * fz;
    float c00y = f[0].y * omz + f[1].y * fz;
    float c01x = f[2].x * omz + f[3].x * fz;
    float c01y = f[2].y * omz + f[3].y * fz;
    float c10x = f[4].x * omz + f[5].x * fz;
    float c10y = f[4].y * omz + f[5].y * fz;
    float c11x = f[6].x * omz + f[7].x * fz;
    float c11y = f[6].y * omz + f[7].y * fz;
    float c0x = c00x * omy + c01x * fy;
    float c0y = c00y * omy + c01y * fy;
    float c1x = c10x * omy + c11x * fy;
    float c1y = c10y * omy + c11y * fy;
    float2 o;
    o.x = c0x * omx + c1x * fx;
    o.y = c0y * omx + c1y * fx;
    return o;
}

// ---------------- Pass 1a: levels 0-1 from LDS dense grids ----------------
// Levels 0,1 have (res+1)^3 = 17^3 / 24^3 reachable cells -> whole level fits
// in LDS (39KB / 110KB) as a dense [x][y][z] grid of hashed values. 110KB
// forces 1 block/CU; r6 ran 256 thr (4 waves/CU, poor hiding). Now 1024 thr
// = 16 waves/CU, same staging volume, same block count (123/level).
template<int R1>
__device__ __forceinline__ void lowlevel_body(
    const float* __restrict__ pos, const float2* __restrict__ table,
    float2* __restrict__ ws, float res, int level, int N, float2* cell)
{
    const int R1sq = R1 * R1;
    unsigned base = (unsigned)level * T_SIZE;

    for (int s = threadIdx.x; s < R1 * R1sq; s += 1024) {
        int x = s / R1sq;            // compile-time divisor -> magic-mul
        int r = s - x * R1sq;
        int y = r / R1;
        int z = r - y * R1;
        unsigned h = ((unsigned)x ^ ((unsigned)y * PRIME1)
                                  ^ ((unsigned)z * PRIME2)) & T_MASK;
        cell[s] = table[base + h];
    }
    __syncthreads();

    int start = blockIdx.x * LOW_PTS;
    int end = start + LOW_PTS; if (end > N) end = N;
    const float HI = 0.999999f;  // float32(1.0 - 1e-6)
    for (int n = start + (int)threadIdx.x; n < end; n += 1024) {
        float px = pos[3 * n + 0], py = pos[3 * n + 1], pz = pos[3 * n + 2];
        float nx = fminf(fmaxf((px + 1.0f) * 0.5f, 0.0f), HI);
        float ny = fminf(fmaxf((py + 1.0f) * 0.5f, 0.0f), HI);
        float nz = fminf(fmaxf((pz + 1.0f) * 0.5f, 0.0f), HI);
        float sx = nx * res, sy = ny * res, sz = nz * res;
        float flx = floorf(sx), fly = floorf(sy), flz = floorf(sz);
        float fx = sx - flx, fy = sy - fly, fz = sz - flz;
        int ix = (int)flx, iy = (int)fly, iz = (int)flz;
        int i000 = (ix * R1 + iy) * R1 + iz;

        // f[i*4+j*2+k] = cell(x+i, y+j, z+k): matches reference OFFSETS order.
        float2 f[8];
        f[0] = cell[i000];
        f[1] = cell[i000 + 1];
        f[2] = cell[i000 + R1];
        f[3] = cell[i000 + R1 + 1];
        f[4] = cell[i000 + R1sq];
        f[5] = cell[i000 + R1sq + 1];
        f[6] = cell[i000 + R1sq + R1];
        f[7] = cell[i000 + R1sq + R1 + 1];

        float2 o = trilerp(f, fx, fy, fz);
        nt_store_f2(o, &ws[(size_t)level * N + n]);  // consecutive n -> full lines
    }
}

__global__ __launch_bounds__(1024, 1) void hashgrid_lowlevel_kernel(
    const float* __restrict__ pos,
    const float2* __restrict__ table,
    float2* __restrict__ ws,
    ResParams rp, int N)
{
    __shared__ float2 cell[LOW_DIM * LOW_DIM * LOW_DIM];  // 110,592 B
    int level = blockIdx.y;           // 0 or 1
    if (level == 0) lowlevel_body<17>(pos, table, ws, rp.r[0], 0, N, cell);
    else            lowlevel_body<24>(pos, table, ws, rp.r[1], 1, N, cell);
}

// ---------------- Pass 1b: level-phased gather, levels 2..15 ----------------
// Round-1 champion structure verbatim (the only variant holding FETCH at
// ~570MB): level = blockIdx.y (+2), dispatch x-fastest -> in-flight window
// spans <=2 levels -> one 4MB table hot per XCD L2. Rounds 3/4 proved any
// non-dispatch-enforced phasing drifts and thrashes (FETCH 2.2-2.7GB).
// Round 5 proved direct scattered 8B output stores RMW-amplify (WRITE 500MB,
// +315us) -> ws staging + coalesced untile is structurally required.
// At 96% of the measured request-rate floor (357 vs 342us model) — done.
__global__ __launch_bounds__(256) void hashgrid_gather_kernel(
    const float* __restrict__ pos,      // [N,3]
    const float2* __restrict__ table,   // [L*T]
    float2* __restrict__ ws,            // [L][N]
    ResParams rp, int N)
{
    int level = blockIdx.y + LOW_LEVELS;
    int t = threadIdx.x;
    int n0 = blockIdx.x * 512 + 2 * t;
    int n1 = n0 + 1;
    bool v0 = n0 < N;
    bool v1 = n1 < N;
    if (!v0) return;

    float res = rp.r[level];
    unsigned base = (unsigned)level * T_SIZE;

    float px0 = pos[3 * n0 + 0], py0 = pos[3 * n0 + 1], pz0 = pos[3 * n0 + 2];
    int m1 = v1 ? n1 : n0;  // safe address for inactive second point
    float px1 = pos[3 * m1 + 0], py1 = pos[3 * m1 + 1], pz1 = pos[3 * m1 + 2];

    CornerSet c0, c1;
    calc_corners(px0, py0, pz0, res, base, c0);
    calc_corners(px1, py1, pz1, res, base, c1);

    float2 f0[8], f1[8];
    load_feats(table, c0, f0);
    load_feats(table, c1, f1);

    float2 o0 = trilerp(f0, c0.fx, c0.fy, c0.fz);
    float2 o1 = trilerp(f1, c1.fx, c1.fy, c1.fz);

    size_t w = (size_t)level * N + n0;   // n0 even -> 16B aligned
    if (v1) {
        f32x4 v; v.x = o0.x; v.y = o0.y; v.z = o1.x; v.w = o1.y;
        nt_store_f4(v, (float*)&ws[w]);
    } else {
        float2 t2; t2.x = o0.x; t2.y = o0.y;
        nt_store_f2(t2, &ws[w]);
    }
}

// ---------------- Pass 2: quad untile ws[L][N] -> out[N][32] ----------------
// One thread per (point-QUAD, level-pair): 4x dwordx4 loads + 4x dwordx4
// stores (2x the ILP of the r2 pair form, half the threads/index math).
// Coalescing preserved both ways:
//   reads:  per row, lanes {m, m+8, ...} cover consecutive 32B chunks
//           -> 256B contiguous per row per wave-instr.
//   writes: store instr k writes point 4q+k; 8 lanes (m=0..7) x 16B fill the
//           point's full 128B line per instr (no partial-line RMW — r5 rule).
__global__ __launch_bounds__(256) void hashgrid_untile_kernel(
    const float2* __restrict__ ws,      // [L][N]
    float* __restrict__ out,            // [N][32] floats
    int N)
{
    int g = blockIdx.x * 256 + threadIdx.x;
    int q = g >> 3;                     // point-quad: points 4q..4q+3
    int m = g & 7;                      // level pair (levels 2m, 2m+1)
    int p0 = 4 * q;
    if (p0 >= N) return;

    const float* wsf = (const float*)ws;
    if (p0 + 3 < N) {
        f32x4 r0 = nt_load_f4(&wsf[((size_t)(2 * m)     * N + p0    ) * 2]); // l=2m   pts p0,p0+1
        f32x4 r1 = nt_load_f4(&wsf[((size_t)(2 * m)     * N + p0 + 2) * 2]); // l=2m   pts p0+2,p0+3
        f32x4 r2 = nt_load_f4(&wsf[((size_t)(2 * m + 1) * N + p0    ) * 2]); // l=2m+1 pts p0,p0+1
        f32x4 r3 = nt_load_f4(&wsf[((size_t)(2 * m + 1) * N + p0 + 2) * 2]); // l=2m+1 pts p0+2,p0+3
        f32x4 v0; v0.x = r0.x; v0.y = r0.y; v0.z = r2.x; v0.w = r2.y;
        f32x4 v1; v1.x = r0.z; v1.y = r0.w; v1.z = r2.z; v1.w = r2.w;
        f32x4 v2; v2.x = r1.x; v2.y = r1.y; v2.z = r3.x; v2.w = r3.y;
        f32x4 v3; v3.x = r1.z; v3.y = r1.w; v3.z = r3.z; v3.w = r3.w;
        nt_store_f4(v0, &out[(size_t)(p0 + 0) * 32 + m * 4]);
        nt_store_f4(v1, &out[(size_t)(p0 + 1) * 32 + m * 4]);
        nt_store_f4(v2, &out[(size_t)(p0 + 2) * 32 + m * 4]);
        nt_store_f4(v3, &out[(size_t)(p0 + 3) * 32 + m * 4]);
    } else {
        for (int k = 0; k < 4 && p0 + k < N; ++k) {
            float2 a = nt_load_f2(&ws[(size_t)(2 * m)     * N + p0 + k]);
            float2 b = nt_load_f2(&ws[(size_t)(2 * m + 1) * N + p0 + k]);
            f32x4 v; v.x = a.x; v.y = a.y; v.z = b.x; v.w = b.y;
            nt_store_f4(v, &out[(size_t)(p0 + k) * 32 + m * 4]);
        }
    }
}

// ---------------- Fallback (ws too small): fused single-pass ----------------
__global__ __launch_bounds__(256) void hashgrid_fused16_kernel(
    const float* __restrict__ pos,
    const float2* __restrict__ table,
    float* __restrict__ out,
    ResParams rp, int N)
{
    int n = blockIdx.x * 256 + threadIdx.x;
    if (n >= N) return;
    float px = pos[3 * n + 0], py = pos[3 * n + 1], pz = pos[3 * n + 2];
    const float HI = 0.999999f;
    float nx = fminf(fmaxf((px + 1.0f) * 0.5f, 0.0f), HI);
    float ny = fminf(fmaxf((py + 1.0f) * 0.5f, 0.0f), HI);
    float nz = fminf(fmaxf((pz + 1.0f) * 0.5f, 0.0f), HI);
    float* po = out + (size_t)n * 32;
#pragma unroll 1
    for (int pr = 0; pr < 8; ++pr) {
        CornerSet c0, c1;
        calc_corners(px, py, pz, rp.r[2 * pr],     (unsigned)(2 * pr) * T_SIZE, c0);
        calc_corners(px, py, pz, rp.r[2 * pr + 1], (unsigned)(2 * pr + 1) * T_SIZE, c1);
        float2 f0[8], f1[8];
        load_feats(table, c0, f0);
        load_feats(table, c1, f1);
        float2 o0 = trilerp(f0, c0.fx, c0.fy, c0.fz);
        float2 o1 = trilerp(f1, c1.fx, c1.fy, c1.fz);
        f32x4 v; v.x = o0.x; v.y = o0.y; v.z = o1.x; v.w = o1.y;
        *reinterpret_cast<f32x4*>(po + 4 * pr) = v;
    }
}

extern "C" void kernel_launch(void* const* d_in, const int* in_sizes, int n_in,
                              void* d_out, int out_size, void* d_ws, size_t ws_size,
                              hipStream_t stream) {
    const float*  pos   = (const float*)d_in[0];
    const float2* table = (const float2*)d_in[1];
    int N = in_sizes[0] / 3;

    ResParams rp;
    double growth = exp((log(2048.0) - log(16.0)) / 15.0);
    for (int l = 0; l < NUM_LEVELS; ++l) {
        rp.r[l] = (float)ceil(16.0 * pow(growth, (double)l));
    }

    size_t ws_needed = (size_t)NUM_LEVELS * (size_t)N * sizeof(float2);
    if (ws_size >= ws_needed) {
        float2* ws = (float2*)d_ws;

        int lowblocks = (N + LOW_PTS - 1) / LOW_PTS;
        dim3 lgrid(lowblocks, LOW_LEVELS);
        hashgrid_lowlevel_kernel<<<lgrid, 1024, 0, stream>>>(pos, table, ws, rp, N);

        int chunks = (N + 511) / 512;           // 2 points per thread
        dim3 ggrid(chunks, NUM_LEVELS - LOW_LEVELS);  // x-fastest => level-phased
        hashgrid_gather_kernel<<<ggrid, 256, 0, stream>>>(pos, table, ws, rp, N);

        long long tthreads = (((long long)N + 3) / 4) * 8;
        int tblocks = (int)((tthreads + 255) / 256);
        hashgrid_untile_kernel<<<tblocks, 256, 0, stream>>>(ws, (float*)d_out, N);
    } else {
        int fb = (N + 255) / 256;
        hashgrid_fused16_kernel<<<fb, 256, 0, stream>>>(
            pos, table, (float*)d_out, rp, N);
    }
}

// Round 8
// 532.641 us; speedup vs baseline: 1.7945x; 1.0372x over previous
//
#include <hip/hip_runtime.h>
#include <math.h>

#define NUM_LEVELS 16
#define T_SIZE (1u << 19)
#define T_MASK (T_SIZE - 1u)
#define PRIME1 2654435761u
#define PRIME2 805459861u

#define LOW_LEVELS 2     // levels 0,1 served from LDS dense grids
#define LOW_PTS 8192     // points per low-level block
#define LOW_DIM 24       // max (res+1) over low levels: res[1]=23

struct ResParams { float r[NUM_LEVELS]; };

typedef float f32x2 __attribute__((ext_vector_type(2)));
typedef float f32x4 __attribute__((ext_vector_type(4)));
typedef _Float16 f16x2 __attribute__((ext_vector_type(2)));
typedef _Float16 f16x4 __attribute__((ext_vector_type(4)));
typedef _Float16 f16x8 __attribute__((ext_vector_type(8)));

__device__ __forceinline__ void nt_store_f4(f32x4 v, float* p) {
    __builtin_nontemporal_store(v, (f32x4*)p);
}
__device__ __forceinline__ void nt_store_h2(f16x2 v, f16x2* p) {
    __builtin_nontemporal_store(v, p);
}
__device__ __forceinline__ void nt_store_h4(f16x4 v, f16x2* p) {
    __builtin_nontemporal_store(v, (f16x4*)p);
}
__device__ __forceinline__ f16x8 nt_load_h8(const f16x2* p) {
    return __builtin_nontemporal_load((const f16x8*)p);
}
__device__ __forceinline__ f16x2 nt_load_h2(const f16x2* p) {
    return __builtin_nontemporal_load(p);
}

// Corner hash indices + fractional weights for one (point, level).
struct CornerSet {
    unsigned idx[8];
    unsigned ux;       // integer x cell coord (parity decides paired loads)
    float fx, fy, fz;
};

__device__ __forceinline__ void calc_corners(
    float px, float py, float pz, float res, unsigned base, CornerSet& cs)
{
    // normalized = (p+1)/(2+1e-8); float32(2+1e-8)==2.0f so *0.5f is bit-identical
    float nx = (px + 1.0f) * 0.5f;
    float ny = (py + 1.0f) * 0.5f;
    float nz = (pz + 1.0f) * 0.5f;
    const float HI = 0.999999f;  // float32(1.0 - 1e-6)
    nx = fminf(fmaxf(nx, 0.0f), HI);
    ny = fminf(fmaxf(ny, 0.0f), HI);
    nz = fminf(fmaxf(nz, 0.0f), HI);

    float sx = nx * res, sy = ny * res, sz = nz * res;
    float flx = floorf(sx), fly = floorf(sy), flz = floorf(sz);
    cs.fx = sx - flx; cs.fy = sy - fly; cs.fz = sz - flz;

    unsigned ux = (unsigned)(int)flx;
    unsigned uy = (unsigned)(int)fly;
    unsigned uz = (unsigned)(int)flz;
    cs.ux = ux;

    unsigned hx0 = ux;            unsigned hx1 = ux + 1u;
    unsigned hy0 = uy * PRIME1;   unsigned hy1 = hy0 + PRIME1;
    unsigned hz0 = uz * PRIME2;   unsigned hz1 = hz0 + PRIME2;

    cs.idx[0] = base + ((hx0 ^ hy0 ^ hz0) & T_MASK);
    cs.idx[1] = base + ((hx0 ^ hy0 ^ hz1) & T_MASK);
    cs.idx[2] = base + ((hx0 ^ hy1 ^ hz0) & T_MASK);
    cs.idx[3] = base + ((hx0 ^ hy1 ^ hz1) & T_MASK);
    cs.idx[4] = base + ((hx1 ^ hy0 ^ hz0) & T_MASK);
    cs.idx[5] = base + ((hx1 ^ hy0 ^ hz1) & T_MASK);
    cs.idx[6] = base + ((hx1 ^ hy1 ^ hz0) & T_MASK);
    cs.idx[7] = base + ((hx1 ^ hy1 ^ hz1) & T_MASK);
}

// PRIMES[0]==1 => for even ux the x1-corner hash is h0^1: the two x-corners of
// each (y,z) pair sit in ADJACENT table slots -> one aligned 16B load covers
// both (4 requests, 64B). Odd ux keeps 8 independent 8B gathers (8 req, 64B).
// Measured request-cost model (r0/r1/r2/r6 fits): c8=3.73ps, c16=4.77ps
// chip-wide => this form is the floor (even: 4*c16, odd: 8*c8).
__device__ __forceinline__ void load_feats(
    const float2* __restrict__ table, const CornerSet& cs, float2 f[8])
{
    if ((cs.ux & 1u) == 0u) {
        const f32x4* t4 = reinterpret_cast<const f32x4*>(table);
#pragma unroll
        for (int j = 0; j < 4; ++j) {
            unsigned i0 = cs.idx[j];            // x0 corner; x1 corner = i0^1
            f32x4 v = t4[i0 >> 1];              // 16B-aligned pair {i0&~1, i0|1}
            float2 lo; lo.x = v.x; lo.y = v.y;  // slot (i0 & ~1)
            float2 hi; hi.x = v.z; hi.y = v.w;  // slot (i0 | 1)
            bool sw = (i0 & 1u) != 0u;
            f[j]     = sw ? hi : lo;            // corner x0 = slot i0
            f[4 + j] = sw ? lo : hi;            // corner x1 = slot i0^1
        }
    } else {
#pragma unroll
        for (int i = 0; i < 8; ++i) f[i] = table[cs.idx[i]];
    }
}

__device__ __forceinline__ float2 trilerp(const float2 f[8], float fx, float fy, float fz)
{
    float omz = 1.0f - fz, omy = 1.0f - fy, omx = 1.0f - fx;
    float c00x = f[0].x * omz + f[1].x * fz;
    float c00y = f[0].y * omz + f[1].y * fz;
    float c01x = f[2].x * omz + f[3].x * fz;
    float c01y = f[2].y * omz + f[3].y * fz;
    float c10x = f[4].x * omz + f[5].x * fz;
    float c10y = f[4].y * omz + f[5].y * fz;
    float c11x = f[6].x * omz + f[7].x * fz;
    float c11y = f[6].y * omz + f[7].y * fz;
    float c0x = c00x * omy + c01x * fy;
    float c0y = c00y * omy + c01y * fy;
    float c1x = c10x * omy + c11x * fy;
    float c1y = c10y * omy + c11y * fy;
    float2 o;
    o.x = c0x * omx + c1x * fx;
    o.y = c0y * omx + c1y * fx;
    return o;
}

// ws is fp16: final per-level outputs, |v| <= ~1.3e-4, fp16 RTE rounding adds
// <=6e-8 abs error vs the 4.77e-7 existing FMA-contraction absmax. Halves the
// ws streaming bytes (gather stores 64MB, untile reads 64MB).
__device__ __forceinline__ f16x2 to_h2(float2 o) {
    f16x2 h; h.x = (_Float16)o.x; h.y = (_Float16)o.y; return h;
}

// ---------------- Pass 1a: levels 0-1 from LDS dense grids ----------------
// Levels 0,1 have (res+1)^3 = 17^3 / 24^3 reachable cells -> whole level fits
// in LDS (39KB / 110KB) as a dense [x][y][z] grid of hashed values. 110KB
// forces 1 block/CU; 1024 thr = 16 waves/CU for latency hiding.
template<int R1>
__device__ __forceinline__ void lowlevel_body(
    const float* __restrict__ pos, const float2* __restrict__ table,
    f16x2* __restrict__ ws, float res, int level, int N, float2* cell)
{
    const int R1sq = R1 * R1;
    unsigned base = (unsigned)level * T_SIZE;

    for (int s = threadIdx.x; s < R1 * R1sq; s += 1024) {
        int x = s / R1sq;            // compile-time divisor -> magic-mul
        int r = s - x * R1sq;
        int y = r / R1;
        int z = r - y * R1;
        unsigned h = ((unsigned)x ^ ((unsigned)y * PRIME1)
                                  ^ ((unsigned)z * PRIME2)) & T_MASK;
        cell[s] = table[base + h];
    }
    __syncthreads();

    int start = blockIdx.x * LOW_PTS;
    int end = start + LOW_PTS; if (end > N) end = N;
    const float HI = 0.999999f;  // float32(1.0 - 1e-6)
    for (int n = start + (int)threadIdx.x; n < end; n += 1024) {
        float px = pos[3 * n + 0], py = pos[3 * n + 1], pz = pos[3 * n + 2];
        float nx = fminf(fmaxf((px + 1.0f) * 0.5f, 0.0f), HI);
        float ny = fminf(fmaxf((py + 1.0f) * 0.5f, 0.0f), HI);
        float nz = fminf(fmaxf((pz + 1.0f) * 0.5f, 0.0f), HI);
        float sx = nx * res, sy = ny * res, sz = nz * res;
        float flx = floorf(sx), fly = floorf(sy), flz = floorf(sz);
        float fx = sx - flx, fy = sy - fly, fz = sz - flz;
        int ix = (int)flx, iy = (int)fly, iz = (int)flz;
        int i000 = (ix * R1 + iy) * R1 + iz;

        // f[i*4+j*2+k] = cell(x+i, y+j, z+k): matches reference OFFSETS order.
        float2 f[8];
        f[0] = cell[i000];
        f[1] = cell[i000 + 1];
        f[2] = cell[i000 + R1];
        f[3] = cell[i000 + R1 + 1];
        f[4] = cell[i000 + R1sq];
        f[5] = cell[i000 + R1sq + 1];
        f[6] = cell[i000 + R1sq + R1];
        f[7] = cell[i000 + R1sq + R1 + 1];

        float2 o = trilerp(f, fx, fy, fz);
        nt_store_h2(to_h2(o), &ws[(size_t)level * N + n]);  // 4B, contiguous n
    }
}

__global__ __launch_bounds__(1024, 1) void hashgrid_lowlevel_kernel(
    const float* __restrict__ pos,
    const float2* __restrict__ table,
    f16x2* __restrict__ ws,
    ResParams rp, int N)
{
    __shared__ float2 cell[LOW_DIM * LOW_DIM * LOW_DIM];  // 110,592 B
    int level = blockIdx.y;           // 0 or 1
    if (level == 0) lowlevel_body<17>(pos, table, ws, rp.r[0], 0, N, cell);
    else            lowlevel_body<24>(pos, table, ws, rp.r[1], 1, N, cell);
}

// ---------------- Pass 1b: level-phased gather, levels 2..15 ----------------
// Round-1 champion structure (the only variant holding FETCH at ~570MB):
// level = blockIdx.y (+2), dispatch x-fastest -> in-flight window spans <=2
// levels -> one 4MB table hot per XCD L2. r3/r4: any non-dispatch-enforced
// phasing drifts and thrashes (FETCH 2.2-2.7GB). r5: scattered direct output
// stores RMW-amplify (WRITE 500MB) -> ws staging structurally required.
// Gather is at 96% of the measured request-rate floor; only change here is
// the fp16 ws store (16B -> 8B per thread).
__global__ __launch_bounds__(256) void hashgrid_gather_kernel(
    const float* __restrict__ pos,      // [N,3]
    const float2* __restrict__ table,   // [L*T]
    f16x2* __restrict__ ws,             // [L][N] fp16 pairs
    ResParams rp, int N)
{
    int level = blockIdx.y + LOW_LEVELS;
    int t = threadIdx.x;
    int n0 = blockIdx.x * 512 + 2 * t;
    int n1 = n0 + 1;
    bool v0 = n0 < N;
    bool v1 = n1 < N;
    if (!v0) return;

    float res = rp.r[level];
    unsigned base = (unsigned)level * T_SIZE;

    float px0 = pos[3 * n0 + 0], py0 = pos[3 * n0 + 1], pz0 = pos[3 * n0 + 2];
    int m1 = v1 ? n1 : n0;  // safe address for inactive second point
    float px1 = pos[3 * m1 + 0], py1 = pos[3 * m1 + 1], pz1 = pos[3 * m1 + 2];

    CornerSet c0, c1;
    calc_corners(px0, py0, pz0, res, base, c0);
    calc_corners(px1, py1, pz1, res, base, c1);

    float2 f0[8], f1[8];
    load_feats(table, c0, f0);
    load_feats(table, c1, f1);

    float2 o0 = trilerp(f0, c0.fx, c0.fy, c0.fz);
    float2 o1 = trilerp(f1, c1.fx, c1.fy, c1.fz);

    size_t w = (size_t)level * N + n0;   // n0 even -> 8B aligned
    if (v1) {
        f16x2 h0 = to_h2(o0), h1 = to_h2(o1);
        f16x4 h; h.x = h0.x; h.y = h0.y; h.z = h1.x; h.w = h1.y;
        nt_store_h4(h, &ws[w]);
    } else {
        nt_store_h2(to_h2(o0), &ws[w]);
    }
}

// ---------------- Pass 2: quad untile ws[L][N] fp16 -> out[N][32] fp32 ------
// Thread = (point-QUAD, level-pair m). Full-line coalescing BOTH ways:
//   reads:  one f16x8 (16B) covers 4 points of one row; same-m lanes sit at
//           16B stride -> 128B contiguous per 8-lane group per instr.
//           (r7's quad form had 32B stride w/ 16B loads = half-full lines.)
//   writes: store k: lanes m=0..7 of a j-group fill all 8 chunks of point
//           4j+k's 128B line (no partial-line RMW — r5 rule).
// 2 loads + 4 stores/thread; 64MB in, 128MB out.
__global__ __launch_bounds__(256) void hashgrid_untile_kernel(
    const f16x2* __restrict__ ws,       // [L][N] fp16 pairs
    float* __restrict__ out,            // [N][32] floats
    int N)
{
    int g = blockIdx.x * 256 + threadIdx.x;
    int q = g >> 3;                     // point-quad: points 4q..4q+3
    int m = g & 7;                      // level pair (levels 2m, 2m+1)
    int p0 = 4 * q;
    if (p0 >= N) return;

    if (p0 + 3 < N) {
        f16x8 a = nt_load_h8(&ws[(size_t)(2 * m)     * N + p0]);  // lvl 2m,   pts p0..p0+3
        f16x8 b = nt_load_h8(&ws[(size_t)(2 * m + 1) * N + p0]);  // lvl 2m+1, pts p0..p0+3
#pragma unroll
        for (int k = 0; k < 4; ++k) {
            f32x4 v;
            v.x = (float)a[2 * k];
            v.y = (float)a[2 * k + 1];
            v.z = (float)b[2 * k];
            v.w = (float)b[2 * k + 1];
            nt_store_f4(v, &out[(size_t)(p0 + k) * 32 + m * 4]);
        }
    } else {
        for (int k = 0; k < 4 && p0 + k < N; ++k) {
            f16x2 a = nt_load_h2(&ws[(size_t)(2 * m)     * N + p0 + k]);
            f16x2 b = nt_load_h2(&ws[(size_t)(2 * m + 1) * N + p0 + k]);
            f32x4 v;
            v.x = (float)a.x; v.y = (float)a.y;
            v.z = (float)b.x; v.w = (float)b.y;
            nt_store_f4(v, &out[(size_t)(p0 + k) * 32 + m * 4]);
        }
    }
}

// ---------------- Fallback (ws too small): fused single-pass, fp32 ----------
__global__ __launch_bounds__(256) void hashgrid_fused16_kernel(
    const float* __restrict__ pos,
    const float2* __restrict__ table,
    float* __restrict__ out,
    ResParams rp, int N)
{
    int n = blockIdx.x * 256 + threadIdx.x;
    if (n >= N) return;
    float px = pos[3 * n + 0], py = pos[3 * n + 1], pz = pos[3 * n + 2];
    const float HI = 0.999999f;
    float nx = fminf(fmaxf((px + 1.0f) * 0.5f, 0.0f), HI);
    float ny = fminf(fmaxf((py + 1.0f) * 0.5f, 0.0f), HI);
    float nz = fminf(fmaxf((pz + 1.0f) * 0.5f, 0.0f), HI);
    float* po = out + (size_t)n * 32;
#pragma unroll 1
    for (int pr = 0; pr < 8; ++pr) {
        CornerSet c0, c1;
        calc_corners(px, py, pz, rp.r[2 * pr],     (unsigned)(2 * pr) * T_SIZE, c0);
        calc_corners(px, py, pz, rp.r[2 * pr + 1], (unsigned)(2 * pr + 1) * T_SIZE, c1);
        float2 f0[8], f1[8];
        load_feats(table, c0, f0);
        load_feats(table, c1, f1);
        float2 o0 = trilerp(f0, c0.fx, c0.fy, c0.fz);
        float2 o1 = trilerp(f1, c1.fx, c1.fy, c1.fz);
        f32x4 v; v.x = o0.x; v.y = o0.y; v.z = o1.x; v.w = o1.y;
        *reinterpret_cast<f32x4*>(po + 4 * pr) = v;
    }
}

extern "C" void kernel_launch(void* const* d_in, const int* in_sizes, int n_in,
                              void* d_out, int out_size, void* d_ws, size_t ws_size,
                              hipStream_t stream) {
    const float*  pos   = (const float*)d_in[0];
    const float2* table = (const float2*)d_in[1];
    int N = in_sizes[0] / 3;

    ResParams rp;
    double growth = exp((log(2048.0) - log(16.0)) / 15.0);
    for (int l = 0; l < NUM_LEVELS; ++l) {
        rp.r[l] = (float)ceil(16.0 * pow(growth, (double)l));
    }

    size_t ws_needed = (size_t)NUM_LEVELS * (size_t)N * sizeof(f16x2);
    if (ws_size >= ws_needed) {
        f16x2* ws = (f16x2*)d_ws;

        int lowblocks = (N + LOW_PTS - 1) / LOW_PTS;
        dim3 lgrid(lowblocks, LOW_LEVELS);
        hashgrid_lowlevel_kernel<<<lgrid, 1024, 0, stream>>>(pos, table, ws, rp, N);

        int chunks = (N + 511) / 512;           // 2 points per thread
        dim3 ggrid(chunks, NUM_LEVELS - LOW_LEVELS);  // x-fastest => level-phased
        hashgrid_gather_kernel<<<ggrid, 256, 0, stream>>>(pos, table, ws, rp, N);

        long long tthreads = (((long long)N + 3) / 4) * 8;
        int tblocks = (int)((tthreads + 255) / 256);
        hashgrid_untile_kernel<<<tblocks, 256, 0, stream>>>(ws, (float*)d_out, N);
    } else {
        int fb = (N + 255) / 256;
        hashgrid_fused16_kernel<<<fb, 256, 0, stream>>>(
            pos, table, (float*)d_out, rp, N);
    }
}